// Round 1
// baseline (46003.479 us; speedup 1.0000x reference)
//
#include <hip/hip_runtime.h>
#include <math.h>

#define NB 32
#define NN 1500
#define NE 24000
#define HIST_L 24
#define PRED_L 24
#define FDIM 31
#define INUM 32
#define HID 256
#define ROWS (NB*NN)   // 48000

__device__ __forceinline__ float sigf(float x){ return 1.0f/(1.0f+expf(-x)); }

// ---------------- precompute: degrees, CSR by dst (deterministic) ----------------
__global__ void k_count(const int* __restrict__ ei, int* deg, int* cnt){
    int e = blockIdx.x*blockDim.x + threadIdx.x;
    if (e < NE){ atomicAdd(&deg[ei[e]], 1); atomicAdd(&cnt[ei[NE+e]], 1); }
}

__global__ void k_prefix(const int* __restrict__ cnt, int* __restrict__ coff){
    int lane = threadIdx.x;            // 64 threads, 1 wave
    const int CH = (NN + 63)/64;       // 24
    int s = 0;
    for (int i=0;i<CH;i++){ int n = lane*CH+i; if (n<NN) s += cnt[n]; }
    int incl = s;
    for (int off=1; off<64; off<<=1){ int v = __shfl_up(incl, off); if (lane>=off) incl += v; }
    int run = incl - s;                // exclusive
    for (int i=0;i<CH;i++){ int n = lane*CH+i; if (n<NN){ coff[n] = run; run += cnt[n]; } }
    if (lane==63) coff[NN] = run;
}

__global__ void k_fill(const int* __restrict__ ei, const int* __restrict__ deg,
                       const int* __restrict__ coff, int* __restrict__ csrc, float* __restrict__ cw){
    int n = blockIdx.x*blockDim.x + threadIdx.x;
    if (n >= NN) return;
    int pos = coff[n];
    int dn = deg[n];
    float disn = dn>0 ? rsqrtf((float)dn) : 0.0f;
    for (int e=0;e<NE;e++){
        if (ei[NE+e]==n){
            int s = ei[e];
            int ds = deg[s];
            float diss = ds>0 ? rsqrtf((float)ds) : 0.0f;
            csrc[pos] = s;
            cw[pos] = -(diss*disn);
            pos++;
        }
    }
}

// ---------------- per-step kernels ----------------
__global__ void k_build_xt(const float* __restrict__ ch0, int bstride, int choff,
                           const float* __restrict__ feats, int tf, float* __restrict__ xt){
    int idx = blockIdx.x*blockDim.x + threadIdx.x;
    if (idx >= ROWS*INUM) return;
    int r = idx >> 5, c = idx & 31;
    int b = r / NN, n = r - b*NN;
    float v;
    if (c == 0) v = ch0[b*bstride + choff + n];
    else        v = feats[((size_t)(b*(HIST_L+PRED_L) + tf)*NN + n)*FDIM + (c-1)];
    xt[idx] = v;
}

// vout = scale * L_hat(vin) - (sub ? sub : 0)
__global__ void k_lx(const float* __restrict__ vin, const int* __restrict__ coff,
                     const int* __restrict__ csrc, const float* __restrict__ cw,
                     const float* __restrict__ sub, float scale, float* __restrict__ vout){
    int idx = blockIdx.x*blockDim.x + threadIdx.x;
    if (idx >= ROWS*INUM) return;
    int r = idx >> 5, d = idx & 31;
    int b = r / NN, n = r - b*NN;
    float acc = 0.f;
    int j0 = coff[n], j1 = coff[n+1];
    const float* vb = vin + (size_t)b*NN*INUM;
    for (int j=j0;j<j1;j++) acc += cw[j] * vb[csrc[j]*INUM + d];
    float res = scale*acc;
    if (sub) res -= sub[idx];
    vout[idx] = res;
}

// g = sigmoid([xt|T1|T2] @ Wc + bc)   (K = 3*32, out 256)
__global__ __launch_bounds__(256) void k_cheb(const float* __restrict__ xt, const float* __restrict__ T1,
                      const float* __restrict__ T2, const float* __restrict__ Wc,
                      const float* __restrict__ bc, float* __restrict__ g){
    __shared__ float As[64][33];
    __shared__ float Bs[32][65];
    int tid = threadIdx.x;
    int tx = tid & 15, ty = tid >> 4;
    int r0 = blockIdx.x * 64;
    int j0 = blockIdx.y * 64;
    float acc[4][4] = {};
    for (int s=0;s<3;s++){
        const float* A = (s==0)?xt:((s==1)?T1:T2);
        for (int l=tid; l<64*32; l+=256){ int rr=l>>5, kk=l&31; As[rr][kk] = A[(size_t)(r0+rr)*INUM + kk]; }
        for (int l=tid; l<32*64; l+=256){ int kk=l>>6, cc=l&63; Bs[kk][cc] = Wc[(size_t)(s*32+kk)*HID + j0+cc]; }
        __syncthreads();
        for (int kk=0;kk<32;kk++){
            float a[4], bv[4];
            #pragma unroll
            for (int i=0;i<4;i++) a[i] = As[ty*4+i][kk];
            #pragma unroll
            for (int j=0;j<4;j++) bv[j] = Bs[kk][tx*4+j];
            #pragma unroll
            for (int i=0;i<4;i++)
                #pragma unroll
                for (int j=0;j<4;j++) acc[i][j] += a[i]*bv[j];
        }
        __syncthreads();
    }
    #pragma unroll
    for (int i=0;i<4;i++){
        int row = r0 + ty*4+i;
        #pragma unroll
        for (int j=0;j<4;j++){
            int col = j0 + tx*4+j;
            g[(size_t)row*HID + col] = sigf(acc[i][j] + bc[col]);
        }
    }
}

// fused GRU cell: hout = (1-z)*n + z*h
__global__ __launch_bounds__(256) void k_gru(const float* __restrict__ xt, const float* __restrict__ g,
                     const float* __restrict__ hin, const float* __restrict__ Wih,
                     const float* __restrict__ bih, const float* __restrict__ Whh,
                     const float* __restrict__ bhh, float* __restrict__ hout){
    __shared__ float As[64][33];
    __shared__ float Ws[3][64][33];
    int tid = threadIdx.x;
    int tx = tid & 15, ty = tid >> 4;
    int r0 = blockIdx.x * 64;
    int j0 = blockIdx.y * 64;
    float ar[4][4]={}, az[4][4]={}, ain[4][4]={}, ahn[4][4]={};
    // phase 1: xg = [xt(32) | g(256)] against W_ih [768,288]
    for (int kc=0; kc<9; kc++){
        int kb = kc*32;
        if (kc==0){
            for (int l=tid;l<2048;l+=256){ int rr=l>>5,kk=l&31; As[rr][kk]=xt[(size_t)(r0+rr)*INUM+kk]; }
        } else {
            for (int l=tid;l<2048;l+=256){ int rr=l>>5,kk=l&31; As[rr][kk]=g[(size_t)(r0+rr)*HID + (kb-32)+kk]; }
        }
        for (int l=tid;l<3*2048;l+=256){ int gi=l>>11; int rem=l&2047; int cc=rem>>5, kk=rem&31;
            Ws[gi][cc][kk] = Wih[(size_t)(j0+cc+gi*HID)*(INUM+HID) + kb+kk]; }
        __syncthreads();
        for (int kk=0;kk<32;kk++){
            float a[4];
            #pragma unroll
            for (int i=0;i<4;i++) a[i]=As[ty*4+i][kk];
            #pragma unroll
            for (int j=0;j<4;j++){
                float wr=Ws[0][tx*4+j][kk], wz=Ws[1][tx*4+j][kk], wn=Ws[2][tx*4+j][kk];
                #pragma unroll
                for (int i=0;i<4;i++){ ar[i][j]+=a[i]*wr; az[i][j]+=a[i]*wz; ain[i][j]+=a[i]*wn; }
            }
        }
        __syncthreads();
    }
    // phase 2: h against W_hh [768,256]
    for (int kc=0;kc<8;kc++){
        int kb=kc*32;
        for (int l=tid;l<2048;l+=256){ int rr=l>>5,kk=l&31; As[rr][kk]=hin[(size_t)(r0+rr)*HID+kb+kk]; }
        for (int l=tid;l<3*2048;l+=256){ int gi=l>>11; int rem=l&2047; int cc=rem>>5, kk=rem&31;
            Ws[gi][cc][kk] = Whh[(size_t)(j0+cc+gi*HID)*HID + kb+kk]; }
        __syncthreads();
        for (int kk=0;kk<32;kk++){
            float a[4];
            #pragma unroll
            for (int i=0;i<4;i++) a[i]=As[ty*4+i][kk];
            #pragma unroll
            for (int j=0;j<4;j++){
                float wr=Ws[0][tx*4+j][kk], wz=Ws[1][tx*4+j][kk], wn=Ws[2][tx*4+j][kk];
                #pragma unroll
                for (int i=0;i<4;i++){ ar[i][j]+=a[i]*wr; az[i][j]+=a[i]*wz; ahn[i][j]+=a[i]*wn; }
            }
        }
        __syncthreads();
    }
    #pragma unroll
    for (int i=0;i<4;i++){
        int row=r0+ty*4+i;
        #pragma unroll
        for (int j=0;j<4;j++){
            int col=j0+tx*4+j;
            float r = sigf(ar[i][j] + bih[col] + bhh[col]);
            float z = sigf(az[i][j] + bih[col+HID] + bhh[col+HID]);
            float nn = tanhf(ain[i][j] + bih[col+2*HID] + r*(ahn[i][j]+bhh[col+2*HID]));
            float ho = hin[(size_t)row*HID+col];
            hout[(size_t)row*HID+col] = (1.f-z)*nn + z*ho;
        }
    }
}

// x_new = h @ Wfc^T + bfc ; write to out[:,p,:,:] and xprev
__global__ void k_fc(const float* __restrict__ h, const float* __restrict__ Wfc,
                     const float* __restrict__ bfc, float* __restrict__ outp,
                     float* __restrict__ xprev, int p){
    int w = threadIdx.x >> 6;
    int lane = threadIdx.x & 63;
    int row = blockIdx.x*4 + w;
    if (row >= ROWS) return;
    const float4* hv = (const float4*)(h + (size_t)row*HID);
    const float4* wv = (const float4*)Wfc;
    float4 a = hv[lane], b = wv[lane];
    float acc = a.x*b.x + a.y*b.y + a.z*b.z + a.w*b.w;
    for (int off=32;off;off>>=1) acc += __shfl_down(acc, off);
    if (lane==0){
        float v = acc + bfc[0];
        int bb = row / NN, n = row - bb*NN;
        outp[(size_t)(bb*PRED_L + p)*NN + n] = v;
        xprev[row] = v;
    }
}

extern "C" void kernel_launch(void* const* d_in, const int* in_sizes, int n_in,
                              void* d_out, int out_size, void* d_ws, size_t ws_size,
                              hipStream_t stream){
    const float* x_hist = (const float*)d_in[0];
    const float* feats  = (const float*)d_in[1];
    const int*   ei     = (const int*)d_in[2];
    const float* Wc     = (const float*)d_in[3];
    const float* bc     = (const float*)d_in[4];
    const float* Wih    = (const float*)d_in[5];
    const float* bih    = (const float*)d_in[6];
    const float* Whh    = (const float*)d_in[7];
    const float* bhh    = (const float*)d_in[8];
    const float* Wfc    = (const float*)d_in[9];
    const float* bfc    = (const float*)d_in[10];
    float* out = (float*)d_out;

    char* wsp = (char*)d_ws;
    size_t off = 0;
    auto alloc = [&](size_t bytes)->char*{
        char* p = wsp + off; off = (off + bytes + 255) & ~(size_t)255; return p;
    };
    int*   deg  = (int*)  alloc(NN*4);
    int*   cnt  = (int*)  alloc(NN*4);
    int*   coff = (int*)  alloc((NN+1)*4);
    int*   csrc = (int*)  alloc(NE*4);
    float* cw   = (float*)alloc(NE*4);
    float* xt   = (float*)alloc((size_t)ROWS*INUM*4);
    float* T1   = (float*)alloc((size_t)ROWS*INUM*4);
    float* T2   = (float*)alloc((size_t)ROWS*INUM*4);
    float* g    = (float*)alloc((size_t)ROWS*HID*4);
    float* hA   = (float*)alloc((size_t)ROWS*HID*4);
    float* hB   = (float*)alloc((size_t)ROWS*HID*4);
    float* xprev= (float*)alloc((size_t)ROWS*4);

    hipMemsetAsync(deg, 0, NN*4, stream);
    hipMemsetAsync(cnt, 0, NN*4, stream);
    hipMemsetAsync(hA, 0, (size_t)ROWS*HID*4, stream);
    k_count<<<(NE+255)/256,256,0,stream>>>(ei, deg, cnt);
    k_prefix<<<1,64,0,stream>>>(cnt, coff);
    k_fill<<<(NN+255)/256,256,0,stream>>>(ei, deg, coff, csrc, cw);

    float* hin = hA; float* hout = hB;
    dim3 gemmGrid(ROWS/64, 4);
    const int NT = (ROWS*INUM+255)/256;

    auto step = [&](const float* ch0, int bstride, int choff, int tf){
        k_build_xt<<<NT,256,0,stream>>>(ch0, bstride, choff, feats, tf, xt);
        k_lx<<<NT,256,0,stream>>>(xt, coff, csrc, cw, nullptr, 1.f, T1);
        k_lx<<<NT,256,0,stream>>>(T1, coff, csrc, cw, xt, 2.f, T2);
        k_cheb<<<gemmGrid,256,0,stream>>>(xt, T1, T2, Wc, bc, g);
        k_gru<<<gemmGrid,256,0,stream>>>(xt, g, hin, Wih, bih, Whh, bhh, hout);
        float* t = hin; hin = hout; hout = t;
    };

    for (int t=0;t<HIST_L-1;t++)
        step(x_hist, HIST_L*NN, t*NN, t+1);
    for (int p=0;p<PRED_L;p++){
        if (p==0) step(x_hist, HIST_L*NN, (HIST_L-1)*NN, HIST_L+p);
        else      step(xprev, NN, 0, HIST_L+p);
        k_fc<<<(ROWS+3)/4,256,0,stream>>>(hin, Wfc, bfc, out, xprev, p);
    }
}

// Round 2
// 14880.940 us; speedup vs baseline: 3.0914x; 3.0914x over previous
//
#include <hip/hip_runtime.h>
#include <hip/hip_bf16.h>
#include <math.h>

#define NB 32
#define NN 1500
#define NE 24000
#define HIST_L 24
#define PRED_L 24
#define FDIM 31
#define INUM 32
#define HID 256
#define ROWS (NB*NN)   // 48000

typedef float f32x4 __attribute__((ext_vector_type(4)));
typedef short bf16x8 __attribute__((ext_vector_type(8)));
typedef short bf16x4 __attribute__((ext_vector_type(4)));

__device__ __forceinline__ float sigf(float x){ return 1.0f/(1.0f+expf(-x)); }
__device__ __forceinline__ unsigned short f2b(float f){
    __hip_bfloat16 h = __float2bfloat16(f);
    return __builtin_bit_cast(unsigned short, h);
}

// ---------------- precompute: degrees, CSR by dst (deterministic) ----------------
__global__ void k_count(const int* __restrict__ ei, int* deg, int* cnt){
    int e = blockIdx.x*blockDim.x + threadIdx.x;
    if (e < NE){ atomicAdd(&deg[ei[e]], 1); atomicAdd(&cnt[ei[NE+e]], 1); }
}

__global__ void k_prefix(const int* __restrict__ cnt, int* __restrict__ coff){
    int lane = threadIdx.x;            // 64 threads, 1 wave
    const int CH = (NN + 63)/64;       // 24
    int s = 0;
    for (int i=0;i<CH;i++){ int n = lane*CH+i; if (n<NN) s += cnt[n]; }
    int incl = s;
    for (int off=1; off<64; off<<=1){ int v = __shfl_up(incl, off); if (lane>=off) incl += v; }
    int run = incl - s;                // exclusive
    for (int i=0;i<CH;i++){ int n = lane*CH+i; if (n<NN){ coff[n] = run; run += cnt[n]; } }
    if (lane==63) coff[NN] = run;
}

__global__ void k_fill(const int* __restrict__ ei, const int* __restrict__ deg,
                       const int* __restrict__ coff, int* __restrict__ csrc, float* __restrict__ cw){
    int n = blockIdx.x*blockDim.x + threadIdx.x;
    if (n >= NN) return;
    int pos = coff[n];
    int dn = deg[n];
    float disn = dn>0 ? rsqrtf((float)dn) : 0.0f;
    for (int e=0;e<NE;e++){
        if (ei[NE+e]==n){
            int s = ei[e];
            int ds = deg[s];
            float diss = ds>0 ? rsqrtf((float)ds) : 0.0f;
            csrc[pos] = s;
            cw[pos] = -(diss*disn);
            pos++;
        }
    }
}

// ---------------- one-time weight conversions ----------------
__global__ void k_f2b(const float* __restrict__ src, unsigned short* __restrict__ dst, int n){
    int i = blockIdx.x*256 + threadIdx.x;
    if (i < n) dst[i] = f2b(src[i]);
}

// Wc [3][32][256] -> Wct [3][256][32] bf16  (B in [col][k] layout)
__global__ void k_wct(const float* __restrict__ Wc, unsigned short* __restrict__ Wct){
    int i = blockIdx.x*256 + threadIdx.x;
    if (i < 3*256*32){
        int s = i/(256*32), rem = i%(256*32), j = rem/32, k = rem%32;
        Wct[i] = f2b(Wc[(size_t)(s*32+k)*256 + j]);
    }
}

// ---------------- per-step kernels ----------------
__global__ void k_build_xt(const float* __restrict__ ch0, int bstride, int choff,
                           const float* __restrict__ feats, int tf,
                           float* __restrict__ xt, unsigned short* __restrict__ xtb){
    int idx = blockIdx.x*blockDim.x + threadIdx.x;
    if (idx >= ROWS*INUM) return;
    int r = idx >> 5, c = idx & 31;
    int b = r / NN, n = r - b*NN;
    float v;
    if (c == 0) v = ch0[b*bstride + choff + n];
    else        v = feats[((size_t)(b*(HIST_L+PRED_L) + tf)*NN + n)*FDIM + (c-1)];
    xt[idx] = v;
    xtb[idx] = f2b(v);
}

// res = scale * L_hat(vin) - (sub ? sub : 0); write fp32 (nullable) and bf16 (nullable)
__global__ void k_lx(const float* __restrict__ vin, const int* __restrict__ coff,
                     const int* __restrict__ csrc, const float* __restrict__ cw,
                     const float* __restrict__ sub, float scale,
                     float* __restrict__ vout, unsigned short* __restrict__ voutb){
    int idx = blockIdx.x*blockDim.x + threadIdx.x;
    if (idx >= ROWS*INUM) return;
    int r = idx >> 5, d = idx & 31;
    int b = r / NN, n = r - b*NN;
    float acc = 0.f;
    int j0 = coff[n], j1 = coff[n+1];
    const float* vb = vin + (size_t)b*NN*INUM;
    for (int j=j0;j<j1;j++) acc += cw[j] * vb[csrc[j]*INUM + d];
    float res = scale*acc;
    if (sub) res -= sub[idx];
    if (vout)  vout[idx]  = res;
    if (voutb) voutb[idx] = f2b(res);
}

// ---------------- MFMA Cheb GEMM: g = sigmoid([xt|T1|T2] @ Wc + bc), bf16 out ----------------
__global__ __launch_bounds__(256) void k_cheb_mfma(
    const unsigned short* __restrict__ xtb, const unsigned short* __restrict__ T1b,
    const unsigned short* __restrict__ T2b, const unsigned short* __restrict__ Wct,
    const float* __restrict__ bc, unsigned short* __restrict__ gb)
{
    __shared__ __align__(16) unsigned short As[128*40];
    __shared__ __align__(16) unsigned short Bs[64*40];
    const int tid = threadIdx.x;
    const int wid = tid >> 6, lane = tid & 63;
    const int wm = wid >> 1, wn = wid & 1;
    const int r0 = blockIdx.x * 128;
    const int j0 = blockIdx.y * 64;
    const int l15 = lane & 15, lhi = lane >> 4;
    const int koff = lhi * 8;

    f32x4 acc[4][2] = {};

    for (int s=0; s<3; s++){
        const unsigned short* A = (s==0)?xtb:((s==1)?T1b:T2b);
        #pragma unroll
        for (int it=0; it<2; it++){
            int idx = tid + it*256;           // 512 chunks of 16B
            int row = idx >> 2, c = idx & 3;
            *(int4*)&As[row*40 + c*8] = *(const int4*)&A[(size_t)(r0+row)*INUM + c*8];
        }
        {
            int col = tid >> 2, c = tid & 3;  // 256 chunks
            *(int4*)&Bs[col*40 + c*8] = *(const int4*)&Wct[(size_t)(s*256 + j0 + col)*32 + c*8];
        }
        __syncthreads();
        bf16x8 b0 = *(const bf16x8*)&Bs[(wn*32 + l15)*40 + koff];
        bf16x8 b1 = *(const bf16x8*)&Bs[(wn*32 + 16 + l15)*40 + koff];
        #pragma unroll
        for (int mi=0; mi<4; mi++){
            bf16x8 am = *(const bf16x8*)&As[(wm*64 + mi*16 + l15)*40 + koff];
            acc[mi][0] = __builtin_amdgcn_mfma_f32_16x16x32_bf16(am, b0, acc[mi][0], 0,0,0);
            acc[mi][1] = __builtin_amdgcn_mfma_f32_16x16x32_bf16(am, b1, acc[mi][1], 0,0,0);
        }
        __syncthreads();
    }
    #pragma unroll
    for (int ni=0; ni<2; ni++){
        int col = j0 + wn*32 + ni*16 + l15;
        float bcv = bc[col];
        #pragma unroll
        for (int mi=0; mi<4; mi++){
            #pragma unroll
            for (int v=0; v<4; v++){
                int row = r0 + wm*64 + mi*16 + lhi*4 + v;
                gb[(size_t)row*HID + col] = f2b(sigf(acc[mi][ni][v] + bcv));
            }
        }
    }
}

// ---------------- MFMA fused GRU cell ----------------
// phase1: [xt(32)|g(256)] @ Wih^T (gates r,z,in) ; phase2: h @ Whh^T (gates r,z,hn)
__global__ __launch_bounds__(256) void k_gru_mfma(
    const unsigned short* __restrict__ xtb, const unsigned short* __restrict__ gb,
    const float* __restrict__ hin,
    const unsigned short* __restrict__ Wbih, const unsigned short* __restrict__ Wbhh,
    const float* __restrict__ bih, const float* __restrict__ bhh,
    float* __restrict__ hout)
{
    __shared__ __align__(16) unsigned short As[128*40];
    __shared__ __align__(16) unsigned short Bs[3*64*40];
    const int tid = threadIdx.x;
    const int wid = tid >> 6, lane = tid & 63;
    const int wm = wid >> 1, wn = wid & 1;
    const int r0 = blockIdx.x * 128;
    const int j0 = blockIdx.y * 64;
    const int l15 = lane & 15, lhi = lane >> 4;
    const int koff = lhi * 8;

    f32x4 ar[4][2]={}, az[4][2]={}, ain[4][2]={}, ahn[4][2]={};

    for (int ks=0; ks<17; ks++){
        // ---- stage A tile (128 rows x 32 k, bf16 in LDS) ----
        if (ks == 0){
            #pragma unroll
            for (int it=0; it<2; it++){
                int idx = tid + it*256;
                int row = idx >> 2, c = idx & 3;
                *(int4*)&As[row*40 + c*8] = *(const int4*)&xtb[(size_t)(r0+row)*INUM + c*8];
            }
        } else if (ks <= 8){
            int cb = (ks-1)*32;
            #pragma unroll
            for (int it=0; it<2; it++){
                int idx = tid + it*256;
                int row = idx >> 2, c = idx & 3;
                *(int4*)&As[row*40 + c*8] = *(const int4*)&gb[(size_t)(r0+row)*HID + cb + c*8];
            }
        } else {
            int cb = (ks-9)*32;
            #pragma unroll
            for (int it=0; it<4; it++){
                int idx = tid + it*256;
                int row = idx >> 3, c = idx & 7;
                float4 v = *(const float4*)&hin[(size_t)(r0+row)*HID + cb + c*4];
                bf16x4 b;
                b[0] = (short)f2b(v.x); b[1] = (short)f2b(v.y);
                b[2] = (short)f2b(v.z); b[3] = (short)f2b(v.w);
                *(bf16x4*)&As[row*40 + c*4] = b;
            }
        }
        // ---- stage B tiles (3 gates x 64 cols x 32 k) ----
        const unsigned short* W = (ks < 9) ? Wbih : Wbhh;
        const int Ksrc = (ks < 9) ? (INUM + HID) : HID;
        const int kb   = (ks < 9) ? ks*32 : (ks-9)*32;
        #pragma unroll
        for (int it=0; it<3; it++){
            int idx = tid + it*256;
            int slab = idx >> 8, rem = idx & 255;
            int col = rem >> 2, c = rem & 3;
            *(int4*)&Bs[(slab*64 + col)*40 + c*8] =
                *(const int4*)&W[(size_t)(j0 + col + slab*HID)*Ksrc + kb + c*8];
        }
        __syncthreads();
        // ---- MFMA ----
        bf16x8 a[4];
        #pragma unroll
        for (int mi=0; mi<4; mi++)
            a[mi] = *(const bf16x8*)&As[(wm*64 + mi*16 + l15)*40 + koff];
        {
            bf16x8 b0 = *(const bf16x8*)&Bs[(0*64 + wn*32 + l15)*40 + koff];
            bf16x8 b1 = *(const bf16x8*)&Bs[(0*64 + wn*32 + 16 + l15)*40 + koff];
            #pragma unroll
            for (int mi=0; mi<4; mi++){
                ar[mi][0] = __builtin_amdgcn_mfma_f32_16x16x32_bf16(a[mi], b0, ar[mi][0],0,0,0);
                ar[mi][1] = __builtin_amdgcn_mfma_f32_16x16x32_bf16(a[mi], b1, ar[mi][1],0,0,0);
            }
        }
        {
            bf16x8 b0 = *(const bf16x8*)&Bs[(1*64 + wn*32 + l15)*40 + koff];
            bf16x8 b1 = *(const bf16x8*)&Bs[(1*64 + wn*32 + 16 + l15)*40 + koff];
            #pragma unroll
            for (int mi=0; mi<4; mi++){
                az[mi][0] = __builtin_amdgcn_mfma_f32_16x16x32_bf16(a[mi], b0, az[mi][0],0,0,0);
                az[mi][1] = __builtin_amdgcn_mfma_f32_16x16x32_bf16(a[mi], b1, az[mi][1],0,0,0);
            }
        }
        {
            bf16x8 b0 = *(const bf16x8*)&Bs[(2*64 + wn*32 + l15)*40 + koff];
            bf16x8 b1 = *(const bf16x8*)&Bs[(2*64 + wn*32 + 16 + l15)*40 + koff];
            if (ks < 9){
                #pragma unroll
                for (int mi=0; mi<4; mi++){
                    ain[mi][0] = __builtin_amdgcn_mfma_f32_16x16x32_bf16(a[mi], b0, ain[mi][0],0,0,0);
                    ain[mi][1] = __builtin_amdgcn_mfma_f32_16x16x32_bf16(a[mi], b1, ain[mi][1],0,0,0);
                }
            } else {
                #pragma unroll
                for (int mi=0; mi<4; mi++){
                    ahn[mi][0] = __builtin_amdgcn_mfma_f32_16x16x32_bf16(a[mi], b0, ahn[mi][0],0,0,0);
                    ahn[mi][1] = __builtin_amdgcn_mfma_f32_16x16x32_bf16(a[mi], b1, ahn[mi][1],0,0,0);
                }
            }
        }
        __syncthreads();
    }
    // ---- fused gate epilogue ----
    #pragma unroll
    for (int ni=0; ni<2; ni++){
        int col = j0 + wn*32 + ni*16 + l15;
        float br = bih[col]       + bhh[col];
        float bz = bih[col+HID]   + bhh[col+HID];
        float bi = bih[col+2*HID];
        float bh = bhh[col+2*HID];
        #pragma unroll
        for (int mi=0; mi<4; mi++){
            #pragma unroll
            for (int v=0; v<4; v++){
                int row = r0 + wm*64 + mi*16 + lhi*4 + v;
                float r  = sigf(ar[mi][ni][v] + br);
                float z  = sigf(az[mi][ni][v] + bz);
                float nn = tanhf(ain[mi][ni][v] + bi + r*(ahn[mi][ni][v] + bh));
                float ho = hin[(size_t)row*HID + col];
                hout[(size_t)row*HID + col] = (1.f - z)*nn + z*ho;
            }
        }
    }
}

// x_new = h @ Wfc^T + bfc ; write to out[:,p,:,:] and xprev
__global__ void k_fc(const float* __restrict__ h, const float* __restrict__ Wfc,
                     const float* __restrict__ bfc, float* __restrict__ outp,
                     float* __restrict__ xprev, int p){
    int w = threadIdx.x >> 6;
    int lane = threadIdx.x & 63;
    int row = blockIdx.x*4 + w;
    if (row >= ROWS) return;
    const float4* hv = (const float4*)(h + (size_t)row*HID);
    const float4* wv = (const float4*)Wfc;
    float4 a = hv[lane], b = wv[lane];
    float acc = a.x*b.x + a.y*b.y + a.z*b.z + a.w*b.w;
    for (int off=32;off;off>>=1) acc += __shfl_down(acc, off);
    if (lane==0){
        float v = acc + bfc[0];
        int bb = row / NN, n = row - bb*NN;
        outp[(size_t)(bb*PRED_L + p)*NN + n] = v;
        xprev[row] = v;
    }
}

extern "C" void kernel_launch(void* const* d_in, const int* in_sizes, int n_in,
                              void* d_out, int out_size, void* d_ws, size_t ws_size,
                              hipStream_t stream){
    const float* x_hist = (const float*)d_in[0];
    const float* feats  = (const float*)d_in[1];
    const int*   ei     = (const int*)d_in[2];
    const float* Wc     = (const float*)d_in[3];
    const float* bc     = (const float*)d_in[4];
    const float* Wih    = (const float*)d_in[5];
    const float* bih    = (const float*)d_in[6];
    const float* Whh    = (const float*)d_in[7];
    const float* bhh    = (const float*)d_in[8];
    const float* Wfc    = (const float*)d_in[9];
    const float* bfc    = (const float*)d_in[10];
    float* out = (float*)d_out;

    char* wsp = (char*)d_ws;
    size_t off = 0;
    auto alloc = [&](size_t bytes)->char*{
        char* p = wsp + off; off = (off + bytes + 255) & ~(size_t)255; return p;
    };
    int*   deg  = (int*)  alloc(NN*4);
    int*   cnt  = (int*)  alloc(NN*4);
    int*   coff = (int*)  alloc((NN+1)*4);
    int*   csrc = (int*)  alloc(NE*4);
    float* cw   = (float*)alloc(NE*4);
    float* xt   = (float*)alloc((size_t)ROWS*INUM*4);
    unsigned short* xtb = (unsigned short*)alloc((size_t)ROWS*INUM*2);
    float* T1   = (float*)alloc((size_t)ROWS*INUM*4);
    unsigned short* T1b = (unsigned short*)alloc((size_t)ROWS*INUM*2);
    unsigned short* T2b = (unsigned short*)alloc((size_t)ROWS*INUM*2);
    unsigned short* gb  = (unsigned short*)alloc((size_t)ROWS*HID*2);
    float* hA   = (float*)alloc((size_t)ROWS*HID*4);
    float* hB   = (float*)alloc((size_t)ROWS*HID*4);
    float* xprev= (float*)alloc((size_t)ROWS*4);
    unsigned short* Wbih = (unsigned short*)alloc((size_t)3*HID*(INUM+HID)*2);
    unsigned short* Wbhh = (unsigned short*)alloc((size_t)3*HID*HID*2);
    unsigned short* Wct  = (unsigned short*)alloc((size_t)3*HID*INUM*2);

    hipMemsetAsync(deg, 0, NN*4, stream);
    hipMemsetAsync(cnt, 0, NN*4, stream);
    hipMemsetAsync(hA, 0, (size_t)ROWS*HID*4, stream);
    k_count<<<(NE+255)/256,256,0,stream>>>(ei, deg, cnt);
    k_prefix<<<1,64,0,stream>>>(cnt, coff);
    k_fill<<<(NN+255)/256,256,0,stream>>>(ei, deg, coff, csrc, cw);

    { int n = 3*HID*(INUM+HID); k_f2b<<<(n+255)/256,256,0,stream>>>(Wih, Wbih, n); }
    { int n = 3*HID*HID;        k_f2b<<<(n+255)/256,256,0,stream>>>(Whh, Wbhh, n); }
    { int n = 3*HID*INUM;       k_wct<<<(n+255)/256,256,0,stream>>>(Wc, Wct); }

    float* hin = hA; float* hout = hB;
    dim3 gemmGrid(ROWS/128, HID/64);
    const int NT = (ROWS*INUM+255)/256;

    auto step = [&](const float* ch0, int bstride, int choff, int tf){
        k_build_xt<<<NT,256,0,stream>>>(ch0, bstride, choff, feats, tf, xt, xtb);
        k_lx<<<NT,256,0,stream>>>(xt, coff, csrc, cw, nullptr, 1.f, T1, T1b);
        k_lx<<<NT,256,0,stream>>>(T1, coff, csrc, cw, xt, 2.f, nullptr, T2b);
        k_cheb_mfma<<<gemmGrid,256,0,stream>>>(xtb, T1b, T2b, Wct, bc, gb);
        k_gru_mfma<<<gemmGrid,256,0,stream>>>(xtb, gb, hin, Wbih, Wbhh, bih, bhh, hout);
        float* t = hin; hin = hout; hout = t;
    };

    for (int t=0;t<HIST_L-1;t++)
        step(x_hist, HIST_L*NN, t*NN, t+1);
    for (int p=0;p<PRED_L;p++){
        if (p==0) step(x_hist, HIST_L*NN, (HIST_L-1)*NN, HIST_L+p);
        else      step(xprev, NN, 0, HIST_L+p);
        k_fc<<<(ROWS+3)/4,256,0,stream>>>(hin, Wfc, bfc, out, xprev, p);
    }
}

// Round 3
// 10567.825 us; speedup vs baseline: 4.3532x; 1.4081x over previous
//
#include <hip/hip_runtime.h>
#include <hip/hip_bf16.h>
#include <math.h>

#define NB 32
#define NN 1500
#define NE 24000
#define HIST_L 24
#define PRED_L 24
#define FDIM 31
#define INUM 32
#define HID 256
#define ROWS (NB*NN)   // 48000
#define XGW 320        // xt(32) + g(256) + pad(32)

typedef float f32x4 __attribute__((ext_vector_type(4)));
typedef short bf16x8 __attribute__((ext_vector_type(8)));

__device__ __forceinline__ float sigf(float x){ return 1.0f/(1.0f+expf(-x)); }
__device__ __forceinline__ unsigned short f2b(float f){
    __hip_bfloat16 h = __float2bfloat16(f);
    return __builtin_bit_cast(unsigned short, h);
}

#define AS1 __attribute__((address_space(1)))
#define AS3 __attribute__((address_space(3)))
__device__ __forceinline__ void gload16(const void* g, void* l){
    __builtin_amdgcn_global_load_lds((const AS1 unsigned int*)g, (AS3 unsigned int*)l, 16, 0, 0);
}

// ---------------- precompute: degrees, CSR by dst (deterministic) ----------------
__global__ void k_count(const int* __restrict__ ei, int* deg, int* cnt){
    int e = blockIdx.x*blockDim.x + threadIdx.x;
    if (e < NE){ atomicAdd(&deg[ei[e]], 1); atomicAdd(&cnt[ei[NE+e]], 1); }
}

__global__ void k_prefix(const int* __restrict__ cnt, int* __restrict__ coff){
    int lane = threadIdx.x;            // 64 threads, 1 wave
    const int CH = (NN + 63)/64;       // 24
    int s = 0;
    for (int i=0;i<CH;i++){ int n = lane*CH+i; if (n<NN) s += cnt[n]; }
    int incl = s;
    for (int off=1; off<64; off<<=1){ int v = __shfl_up(incl, off); if (lane>=off) incl += v; }
    int run = incl - s;                // exclusive
    for (int i=0;i<CH;i++){ int n = lane*CH+i; if (n<NN){ coff[n] = run; run += cnt[n]; } }
    if (lane==63) coff[NN] = run;
}

__global__ void k_fill(const int* __restrict__ ei, const int* __restrict__ deg,
                       const int* __restrict__ coff, int* __restrict__ csrc, float* __restrict__ cw){
    int n = blockIdx.x*blockDim.x + threadIdx.x;
    if (n >= NN) return;
    int pos = coff[n];
    int dn = deg[n];
    float disn = dn>0 ? rsqrtf((float)dn) : 0.0f;
    for (int e=0;e<NE;e++){
        if (ei[NE+e]==n){
            int s = ei[e];
            int ds = deg[s];
            float diss = ds>0 ? rsqrtf((float)ds) : 0.0f;
            csrc[pos] = s;
            cw[pos] = -(diss*disn);
            pos++;
        }
    }
}

// ---------------- one-time weight conversions ----------------
// Wih [768][288] -> [768][320] bf16, zero pad
__global__ void k_wihr(const float* __restrict__ W, unsigned short* __restrict__ Wr){
    int i = blockIdx.x*256 + threadIdx.x;
    if (i < 768*XGW){
        int r = i/XGW, c = i - r*XGW;
        Wr[i] = (c < INUM+HID) ? f2b(W[(size_t)r*(INUM+HID) + c]) : (unsigned short)0;
    }
}
__global__ void k_f2b(const float* __restrict__ src, unsigned short* __restrict__ dst, int n){
    int i = blockIdx.x*256 + threadIdx.x;
    if (i < n) dst[i] = f2b(src[i]);
}
// Wc [3][32][256] -> Wct [3][256][32] bf16  (B in [col][k] layout)
__global__ void k_wct(const float* __restrict__ Wc, unsigned short* __restrict__ Wct){
    int i = blockIdx.x*256 + threadIdx.x;
    if (i < 3*256*32){
        int s = i/(256*32), rem = i%(256*32), j = rem/32, k = rem%32;
        Wct[i] = f2b(Wc[(size_t)(s*32+k)*256 + j]);
    }
}

// ---------------- per-step small kernels ----------------
__global__ void k_build_xt(const float* __restrict__ ch0, int bstride, int choff,
                           const float* __restrict__ feats, int tf,
                           float* __restrict__ xt, unsigned short* __restrict__ xg){
    int idx = blockIdx.x*blockDim.x + threadIdx.x;
    if (idx >= ROWS*INUM) return;
    int r = idx >> 5, c = idx & 31;
    int b = r / NN, n = r - b*NN;
    float v;
    if (c == 0) v = ch0[b*bstride + choff + n];
    else        v = feats[((size_t)(b*(HIST_L+PRED_L) + tf)*NN + n)*FDIM + (c-1)];
    xt[idx] = v;
    xg[(size_t)r*XGW + c] = f2b(v);
}

// res = scale * L_hat(vin) - (sub ? sub : 0); write fp32 (nullable) and bf16 (nullable, stride 32)
__global__ void k_lx(const float* __restrict__ vin, const int* __restrict__ coff,
                     const int* __restrict__ csrc, const float* __restrict__ cw,
                     const float* __restrict__ sub, float scale,
                     float* __restrict__ vout, unsigned short* __restrict__ voutb){
    int idx = blockIdx.x*blockDim.x + threadIdx.x;
    if (idx >= ROWS*INUM) return;
    int r = idx >> 5, d = idx & 31;
    int b = r / NN, n = r - b*NN;
    float acc = 0.f;
    int j0 = coff[n], j1 = coff[n+1];
    const float* vb = vin + (size_t)b*NN*INUM;
    for (int j=j0;j<j1;j++) acc += cw[j] * vb[csrc[j]*INUM + d];
    float res = scale*acc;
    if (sub) res -= sub[idx];
    if (vout)  vout[idx]  = res;
    if (voutb) voutb[idx] = f2b(res);
}

// ---------------- MFMA Cheb GEMM: xg[:,32:288] = sigmoid([xt|T1|T2] @ Wc + bc) ----------------
__global__ __launch_bounds__(256) void k_cheb_mfma(
    const unsigned short* __restrict__ xg, const unsigned short* __restrict__ T1b,
    const unsigned short* __restrict__ T2b, const unsigned short* __restrict__ Wct,
    const float* __restrict__ bc, unsigned short* __restrict__ gout)
{
    __shared__ __align__(16) unsigned short As[128*40];
    __shared__ __align__(16) unsigned short Bs[64*40];
    const int tid = threadIdx.x;
    const int wid = tid >> 6, lane = tid & 63;
    const int wm = wid >> 1, wn = wid & 1;
    const int r0 = blockIdx.x * 128;
    const int j0 = blockIdx.y * 64;
    const int l15 = lane & 15, lhi = lane >> 4;
    const int koff = lhi * 8;

    f32x4 acc[4][2] = {};

    for (int s=0; s<3; s++){
        const unsigned short* A = (s==0)?xg:((s==1)?T1b:T2b);
        const int AS = (s==0)?XGW:INUM;
        #pragma unroll
        for (int it=0; it<2; it++){
            int idx = tid + it*256;           // 512 chunks of 16B
            int row = idx >> 2, c = idx & 3;
            *(int4*)&As[row*40 + c*8] = *(const int4*)&A[(size_t)(r0+row)*AS + c*8];
        }
        {
            int col = tid >> 2, c = tid & 3;  // 256 chunks
            *(int4*)&Bs[col*40 + c*8] = *(const int4*)&Wct[(size_t)(s*256 + j0 + col)*32 + c*8];
        }
        __syncthreads();
        bf16x8 b0 = *(const bf16x8*)&Bs[(wn*32 + l15)*40 + koff];
        bf16x8 b1 = *(const bf16x8*)&Bs[(wn*32 + 16 + l15)*40 + koff];
        #pragma unroll
        for (int mi=0; mi<4; mi++){
            bf16x8 am = *(const bf16x8*)&As[(wm*64 + mi*16 + l15)*40 + koff];
            acc[mi][0] = __builtin_amdgcn_mfma_f32_16x16x32_bf16(am, b0, acc[mi][0], 0,0,0);
            acc[mi][1] = __builtin_amdgcn_mfma_f32_16x16x32_bf16(am, b1, acc[mi][1], 0,0,0);
        }
        __syncthreads();
    }
    #pragma unroll
    for (int ni=0; ni<2; ni++){
        int col = j0 + wn*32 + ni*16 + l15;
        float bcv = bc[col];
        #pragma unroll
        for (int mi=0; mi<4; mi++){
            #pragma unroll
            for (int v=0; v<4; v++){
                size_t row = r0 + wm*64 + mi*16 + lhi*4 + v;
                gout[row*XGW + 32 + col] = f2b(sigf(acc[mi][ni][v] + bcv));
            }
        }
    }
}

// ---------------- MFMA GRU tile compute (BK=64, swizzled LDS) ----------------
__device__ __forceinline__ void gru_tile(const unsigned short* As, const unsigned short* Bs,
    int wm, int wn, int l15, int q0, int q1,
    f32x4 (&ar)[4][2], f32x4 (&az)[4][2], f32x4 (&a3)[4][2])
{
    bf16x8 a[4][2];
    #pragma unroll
    for (int mi=0;mi<4;mi++){
        int rb = (wm*64 + mi*16 + l15)*64;
        a[mi][0] = *(const bf16x8*)&As[rb + q0];
        a[mi][1] = *(const bf16x8*)&As[rb + q1];
    }
    #pragma unroll
    for (int slab=0; slab<3; slab++){
        bf16x8 b[2][2];
        #pragma unroll
        for (int ni=0; ni<2; ni++){
            int cb = (slab*64 + wn*32 + ni*16 + l15)*64;
            b[ni][0] = *(const bf16x8*)&Bs[cb + q0];
            b[ni][1] = *(const bf16x8*)&Bs[cb + q1];
        }
        f32x4 (&acc)[4][2] = (slab==0)?ar:((slab==1)?az:a3);
        #pragma unroll
        for (int kh=0; kh<2; kh++)
            #pragma unroll
            for (int mi=0; mi<4; mi++)
                #pragma unroll
                for (int ni=0; ni<2; ni++)
                    acc[mi][ni] = __builtin_amdgcn_mfma_f32_16x16x32_bf16(a[mi][kh], b[ni][kh], acc[mi][ni],0,0,0);
    }
}

// fused GRU cell, gload_lds staging. h updated in place (fp32); hbout = bf16 copy.
__global__ __launch_bounds__(256,2) void k_gru2(
    const unsigned short* __restrict__ xg, const unsigned short* __restrict__ hbin,
    float* __restrict__ h,
    const unsigned short* __restrict__ Wihr, const unsigned short* __restrict__ Whhr,
    const float* __restrict__ bih, const float* __restrict__ bhh,
    unsigned short* __restrict__ hbout)
{
    __shared__ __align__(16) unsigned short As[128*64];   // 16KB
    __shared__ __align__(16) unsigned short Bs[192*64];   // 24KB
    const int tid = threadIdx.x, wid = tid>>6, lane = tid&63;
    const int wm = wid>>1, wn = wid&1;
    const int r0 = blockIdx.x*128, j0 = blockIdx.y*64;
    const int l15 = lane&15, lhi = lane>>4, x7 = l15&7;
    const int q0 = ((lhi^x7))*8, q1 = q0^32;              // ushort offsets within row
    const int swz = (((lane&7)^(lane>>3)))*16;            // byte chunk swizzle
    const int lr = lane>>3;

    f32x4 ar[4][2]={}, az[4][2]={}, ain[4][2]={}, ahn[4][2]={};

    // ---------- phase 1: A=xg (stride 640B), B=Wihr (stride 640B), 5 K-steps ----------
    for (int ks=0; ks<5; ks++){
        __syncthreads();
        {
            const char* Ab = (const char*)xg + (size_t)r0*640 + ks*128 + (size_t)lr*640 + swz;
            char* Ld = (char*)As + wid*4096;
            #pragma unroll
            for (int i=0;i<4;i++)
                gload16(Ab + (size_t)(wid*32 + i*8)*640, Ld + i*1024);
        }
        {
            const char* Bb = (const char*)Wihr + ks*128 + (size_t)lr*640 + swz;
            #pragma unroll
            for (int i=0;i<6;i++){
                int j = wid*6 + i; int slab = j>>3; int c0 = (j&7)*8;
                gload16(Bb + (size_t)(slab*256 + j0 + c0)*640, (char*)Bs + j*1024);
            }
        }
        __syncthreads();
        gru_tile(As, Bs, wm, wn, l15, q0, q1, ar, az, ain);
    }
    // ---------- phase 2: A=hbin (stride 512B), B=Whhr (stride 512B), 4 K-steps ----------
    for (int ks=0; ks<4; ks++){
        __syncthreads();
        {
            const char* Ab = (const char*)hbin + (size_t)r0*512 + ks*128 + (size_t)lr*512 + swz;
            char* Ld = (char*)As + wid*4096;
            #pragma unroll
            for (int i=0;i<4;i++)
                gload16(Ab + (size_t)(wid*32 + i*8)*512, Ld + i*1024);
        }
        {
            const char* Bb = (const char*)Whhr + ks*128 + (size_t)lr*512 + swz;
            #pragma unroll
            for (int i=0;i<6;i++){
                int j = wid*6 + i; int slab = j>>3; int c0 = (j&7)*8;
                gload16(Bb + (size_t)(slab*256 + j0 + c0)*512, (char*)Bs + j*1024);
            }
        }
        __syncthreads();
        gru_tile(As, Bs, wm, wn, l15, q0, q1, ar, az, ahn);
    }
    // ---------- fused gate epilogue ----------
    #pragma unroll
    for (int ni=0; ni<2; ni++){
        int col = j0 + wn*32 + ni*16 + l15;
        float br = bih[col]       + bhh[col];
        float bz = bih[col+HID]   + bhh[col+HID];
        float bi = bih[col+2*HID];
        float bh = bhh[col+2*HID];
        #pragma unroll
        for (int mi=0; mi<4; mi++){
            #pragma unroll
            for (int v=0; v<4; v++){
                size_t row = r0 + wm*64 + mi*16 + lhi*4 + v;
                float r  = sigf(ar[mi][ni][v] + br);
                float z  = sigf(az[mi][ni][v] + bz);
                float nn = tanhf(ain[mi][ni][v] + bi + r*(ahn[mi][ni][v] + bh));
                float ho = h[row*HID + col];
                float hv = (1.f - z)*nn + z*ho;
                h[row*HID + col] = hv;
                hbout[row*HID + col] = f2b(hv);
            }
        }
    }
}

// x_new = h @ Wfc^T + bfc ; write to out[:,p,:,:] and xprev
__global__ void k_fc(const float* __restrict__ h, const float* __restrict__ Wfc,
                     const float* __restrict__ bfc, float* __restrict__ outp,
                     float* __restrict__ xprev, int p){
    int w = threadIdx.x >> 6;
    int lane = threadIdx.x & 63;
    int row = blockIdx.x*4 + w;
    if (row >= ROWS) return;
    const float4* hv = (const float4*)(h + (size_t)row*HID);
    const float4* wv = (const float4*)Wfc;
    float4 a = hv[lane], b = wv[lane];
    float acc = a.x*b.x + a.y*b.y + a.z*b.z + a.w*b.w;
    for (int off=32;off;off>>=1) acc += __shfl_down(acc, off);
    if (lane==0){
        float v = acc + bfc[0];
        int bb = row / NN, n = row - bb*NN;
        outp[(size_t)(bb*PRED_L + p)*NN + n] = v;
        xprev[row] = v;
    }
}

extern "C" void kernel_launch(void* const* d_in, const int* in_sizes, int n_in,
                              void* d_out, int out_size, void* d_ws, size_t ws_size,
                              hipStream_t stream){
    const float* x_hist = (const float*)d_in[0];
    const float* feats  = (const float*)d_in[1];
    const int*   ei     = (const int*)d_in[2];
    const float* Wc     = (const float*)d_in[3];
    const float* bc     = (const float*)d_in[4];
    const float* Wih    = (const float*)d_in[5];
    const float* bih    = (const float*)d_in[6];
    const float* Whh    = (const float*)d_in[7];
    const float* bhh    = (const float*)d_in[8];
    const float* Wfc    = (const float*)d_in[9];
    const float* bfc    = (const float*)d_in[10];
    float* out = (float*)d_out;

    char* wsp = (char*)d_ws;
    size_t off = 0;
    auto alloc = [&](size_t bytes)->char*{
        char* p = wsp + off; off = (off + bytes + 255) & ~(size_t)255; return p;
    };
    int*   deg  = (int*)  alloc(NN*4);
    int*   cnt  = (int*)  alloc(NN*4);
    int*   coff = (int*)  alloc((NN+1)*4);
    int*   csrc = (int*)  alloc(NE*4);
    float* cw   = (float*)alloc(NE*4);
    float* xt   = (float*)alloc((size_t)ROWS*INUM*4);
    float* T1   = (float*)alloc((size_t)ROWS*INUM*4);
    unsigned short* T1b = (unsigned short*)alloc((size_t)ROWS*INUM*2);
    unsigned short* T2b = (unsigned short*)alloc((size_t)ROWS*INUM*2);
    unsigned short* xgb = (unsigned short*)alloc((size_t)ROWS*XGW*2);
    float* h    = (float*)alloc((size_t)ROWS*HID*4);
    unsigned short* hbA = (unsigned short*)alloc((size_t)ROWS*HID*2);
    unsigned short* hbB = (unsigned short*)alloc((size_t)ROWS*HID*2);
    float* xprev= (float*)alloc((size_t)ROWS*4);
    unsigned short* Wihr = (unsigned short*)alloc((size_t)768*XGW*2);
    unsigned short* Whhr = (unsigned short*)alloc((size_t)768*HID*2);
    unsigned short* Wct  = (unsigned short*)alloc((size_t)3*HID*INUM*2);

    hipMemsetAsync(deg, 0, NN*4, stream);
    hipMemsetAsync(cnt, 0, NN*4, stream);
    hipMemsetAsync(h,   0, (size_t)ROWS*HID*4, stream);
    hipMemsetAsync(hbA, 0, (size_t)ROWS*HID*2, stream);
    hipMemsetAsync(hbB, 0, (size_t)ROWS*HID*2, stream);
    hipMemsetAsync(xgb, 0, (size_t)ROWS*XGW*2, stream);   // zero pad cols persist

    k_count<<<(NE+255)/256,256,0,stream>>>(ei, deg, cnt);
    k_prefix<<<1,64,0,stream>>>(cnt, coff);
    k_fill<<<(NN+255)/256,256,0,stream>>>(ei, deg, coff, csrc, cw);

    { int n = 768*XGW; k_wihr<<<(n+255)/256,256,0,stream>>>(Wih, Wihr); }
    { int n = 768*HID; k_f2b<<<(n+255)/256,256,0,stream>>>(Whh, Whhr, n); }
    { int n = 3*HID*INUM; k_wct<<<(n+255)/256,256,0,stream>>>(Wc, Wct); }

    unsigned short* hbin = hbA; unsigned short* hbout = hbB;
    dim3 gemmGrid(ROWS/128, HID/64);
    const int NT = (ROWS*INUM+255)/256;

    auto step = [&](const float* ch0, int bstride, int choff, int tf){
        k_build_xt<<<NT,256,0,stream>>>(ch0, bstride, choff, feats, tf, xt, xgb);
        k_lx<<<NT,256,0,stream>>>(xt, coff, csrc, cw, nullptr, 1.f, T1, T1b);
        k_lx<<<NT,256,0,stream>>>(T1, coff, csrc, cw, xt, 2.f, nullptr, T2b);
        k_cheb_mfma<<<gemmGrid,256,0,stream>>>(xgb, T1b, T2b, Wct, bc, xgb);
        k_gru2<<<gemmGrid,256,0,stream>>>(xgb, hbin, h, Wihr, Whhr, bih, bhh, hbout);
        unsigned short* t = hbin; hbin = hbout; hbout = t;
    };

    for (int t=0;t<HIST_L-1;t++)
        step(x_hist, HIST_L*NN, t*NN, t+1);
    for (int p=0;p<PRED_L;p++){
        if (p==0) step(x_hist, HIST_L*NN, (HIST_L-1)*NN, HIST_L+p);
        else      step(xprev, NN, 0, HIST_L+p);
        k_fc<<<(ROWS+3)/4,256,0,stream>>>(h, Wfc, bfc, out, xprev, p);
    }
}

// Round 4
// 9122.630 us; speedup vs baseline: 5.0428x; 1.1584x over previous
//
#include <hip/hip_runtime.h>
#include <hip/hip_bf16.h>
#include <math.h>

#define NB 32
#define NN 1500
#define NE 24000
#define HIST_L 24
#define PRED_L 24
#define FDIM 31
#define INUM 32
#define HID 256
#define ROWS (NB*NN)   // 48000
#define XGW 288        // xt(32) + g(256)
#define CTXW 96        // xt | T1 | T2

typedef float f32x4 __attribute__((ext_vector_type(4)));
typedef short bf16x8 __attribute__((ext_vector_type(8)));
typedef short bf16x4 __attribute__((ext_vector_type(4)));

__device__ __forceinline__ float sigf(float x){ return 1.0f/(1.0f+expf(-x)); }
__device__ __forceinline__ unsigned short f2b(float f){
    __hip_bfloat16 h = __float2bfloat16(f);
    return __builtin_bit_cast(unsigned short, h);
}

#define AS1 __attribute__((address_space(1)))
#define AS3 __attribute__((address_space(3)))
__device__ __forceinline__ void gload16(const void* g, void* l){
    __builtin_amdgcn_global_load_lds((const AS1 unsigned int*)g, (AS3 unsigned int*)l, 16, 0, 0);
}

// ---------------- precompute: degrees, CSR by dst (deterministic) ----------------
__global__ void k_count(const int* __restrict__ ei, int* deg, int* cnt){
    int e = blockIdx.x*blockDim.x + threadIdx.x;
    if (e < NE){ atomicAdd(&deg[ei[e]], 1); atomicAdd(&cnt[ei[NE+e]], 1); }
}

__global__ void k_prefix(const int* __restrict__ cnt, int* __restrict__ coff){
    int lane = threadIdx.x;            // 64 threads, 1 wave
    const int CH = (NN + 63)/64;       // 24
    int s = 0;
    for (int i=0;i<CH;i++){ int n = lane*CH+i; if (n<NN) s += cnt[n]; }
    int incl = s;
    for (int off=1; off<64; off<<=1){ int v = __shfl_up(incl, off); if (lane>=off) incl += v; }
    int run = incl - s;                // exclusive
    for (int i=0;i<CH;i++){ int n = lane*CH+i; if (n<NN){ coff[n] = run; run += cnt[n]; } }
    if (lane==63) coff[NN] = run;
}

__global__ void k_fill(const int* __restrict__ ei, const int* __restrict__ deg,
                       const int* __restrict__ coff, int* __restrict__ csrc, float* __restrict__ cw){
    int n = blockIdx.x*blockDim.x + threadIdx.x;
    if (n >= NN) return;
    int pos = coff[n];
    int dn = deg[n];
    float disn = dn>0 ? rsqrtf((float)dn) : 0.0f;
    for (int e=0;e<NE;e++){
        if (ei[NE+e]==n){
            int s = ei[e];
            int ds = deg[s];
            float diss = ds>0 ? rsqrtf((float)ds) : 0.0f;
            csrc[pos] = s;
            cw[pos] = -(diss*disn);
            pos++;
        }
    }
}

// ---------------- one-time weight conversions ----------------
__global__ void k_f2b(const float* __restrict__ src, unsigned short* __restrict__ dst, int n){
    int i = blockIdx.x*256 + threadIdx.x;
    if (i < n) dst[i] = f2b(src[i]);
}
// Wc flat [96][256] -> Wctr [256][96] bf16
__global__ void k_wctr(const float* __restrict__ Wc, unsigned short* __restrict__ W){
    int i = blockIdx.x*256 + threadIdx.x;
    if (i < 256*96){
        int j = i/96, k = i - j*96;
        W[i] = f2b(Wc[(size_t)k*256 + j]);
    }
}

// ---------------- per-step small kernels ----------------
__global__ void k_build_xt(const float* __restrict__ ch0, int bstride, int choff,
                           const float* __restrict__ feats, int tf,
                           float* __restrict__ xt, unsigned short* __restrict__ ctx,
                           unsigned short* __restrict__ xg){
    int idx = blockIdx.x*blockDim.x + threadIdx.x;
    if (idx >= ROWS*INUM) return;
    int r = idx >> 5, c = idx & 31;
    int b = r / NN, n = r - b*NN;
    float v;
    if (c == 0) v = ch0[b*bstride + choff + n];
    else        v = feats[((size_t)(b*(HIST_L+PRED_L) + tf)*NN + n)*FDIM + (c-1)];
    xt[idx] = v;
    unsigned short bv = f2b(v);
    ctx[(size_t)r*CTXW + c] = bv;
    xg[(size_t)r*XGW + c] = bv;
}

// float4-vectorized Lx: res = scale*L_hat(vin) - (sub?sub:0); fp32 out nullable; bf16 into ctx col slice
__global__ void k_lx4(const float* __restrict__ vin, const int* __restrict__ coff,
                      const int* __restrict__ csrc, const float* __restrict__ cw,
                      const float* __restrict__ sub, float scale,
                      float* __restrict__ vout, unsigned short* __restrict__ ctxo){
    int idx = blockIdx.x*256 + threadIdx.x;
    if (idx >= ROWS*8) return;
    int r = idx >> 3, l8 = idx & 7;
    int b = r / NN, n = r - b*NN;
    int j0 = coff[n], j1 = coff[n+1];
    const float4* vb = (const float4*)(vin + (size_t)b*NN*INUM);
    float ax=0.f, ay=0.f, az=0.f, aw=0.f;
    for (int j=j0;j<j1;j++){
        float w = cw[j];
        float4 v = vb[csrc[j]*8 + l8];
        ax += w*v.x; ay += w*v.y; az += w*v.z; aw += w*v.w;
    }
    ax *= scale; ay *= scale; az *= scale; aw *= scale;
    if (sub){
        float4 s = ((const float4*)sub)[idx];
        ax -= s.x; ay -= s.y; az -= s.z; aw -= s.w;
    }
    if (vout){
        float4 o; o.x=ax; o.y=ay; o.z=az; o.w=aw;
        ((float4*)vout)[idx] = o;
    }
    bf16x4 ob;
    ob[0]=(short)f2b(ax); ob[1]=(short)f2b(ay); ob[2]=(short)f2b(az); ob[3]=(short)f2b(aw);
    *(bf16x4*)&ctxo[(size_t)r*CTXW + l8*4] = ob;
}

// ---------------- 2-phase Cheb GEMM: xg[:,32:288] = sigmoid(ctx @ Wctr^T + bc) ----------------
__global__ __launch_bounds__(256) void k_cheb2(
    const unsigned short* __restrict__ ctx, const unsigned short* __restrict__ Wctr,
    const float* __restrict__ bc, unsigned short* __restrict__ xg)
{
    __shared__ __align__(16) unsigned short As[2][128*32];  // 2 x 8KB
    __shared__ __align__(16) unsigned short Bs[2][64*32];   // 2 x 4KB
    const int tid = threadIdx.x, wid = tid>>6, lane = tid&63;
    const int wm = wid>>1, wn = wid&1;
    const int r0 = blockIdx.x*128, j0 = blockIdx.y*64;
    const int l15 = lane&15, lhi = lane>>4;
    const int cl = lane>>2;
    const int swz = ((lane&3) ^ (cl&3))*16;
    const int q = (lhi ^ (l15&3))*8;

    auto stA = [&](int ks, int bs){
        char* Ld = (char*)&As[bs][0] + wid*2048;
        #pragma unroll
        for (int i=0;i<2;i++){
            int row = wid*32 + i*16 + cl;
            gload16((const char*)ctx + (size_t)(r0+row)*192 + ks*64 + swz, Ld + i*1024);
        }
    };
    auto stB = [&](int ks, int bs){
        char* Ld = (char*)&Bs[bs][0] + wid*1024;
        int col = j0 + wid*16 + cl;
        gload16((const char*)Wctr + (size_t)col*192 + ks*64 + swz, Ld);
    };

    f32x4 acc[4][2] = {};
    stA(0,0); stB(0,0);
    __syncthreads();
    for (int ks=0; ks<3; ks++){
        int cur = ks&1;
        if (ks<2){ stA(ks+1, cur^1); stB(ks+1, cur^1); }
        const unsigned short* Ap = &As[cur][0];
        const unsigned short* Bp = &Bs[cur][0];
        bf16x8 b0 = *(const bf16x8*)&Bp[(wn*32 + l15)*32 + q];
        bf16x8 b1 = *(const bf16x8*)&Bp[(wn*32 + 16 + l15)*32 + q];
        #pragma unroll
        for (int mi=0;mi<4;mi++){
            bf16x8 am = *(const bf16x8*)&Ap[(wm*64+mi*16+l15)*32 + q];
            acc[mi][0] = __builtin_amdgcn_mfma_f32_16x16x32_bf16(am, b0, acc[mi][0],0,0,0);
            acc[mi][1] = __builtin_amdgcn_mfma_f32_16x16x32_bf16(am, b1, acc[mi][1],0,0,0);
        }
        __syncthreads();
    }
    #pragma unroll
    for (int ni=0; ni<2; ni++){
        int col = j0 + wn*32 + ni*16 + l15;
        float bcv = bc[col];
        #pragma unroll
        for (int mi=0; mi<4; mi++){
            #pragma unroll
            for (int v=0; v<4; v++){
                size_t row = r0 + wm*64 + mi*16 + lhi*4 + v;
                xg[row*XGW + 32 + col] = f2b(sigf(acc[mi][ni][v] + bcv));
            }
        }
    }
}

// ---------------- GRU tile compute (BK=32) ----------------
__device__ __forceinline__ void gtile(const unsigned short* Ap, const unsigned short* Bp,
    int wm, int wn, int l15, int q,
    f32x4 (&ar)[4][2], f32x4 (&az)[4][2], f32x4 (&a3)[4][2])
{
    bf16x8 a[4];
    #pragma unroll
    for (int mi=0;mi<4;mi++)
        a[mi] = *(const bf16x8*)&Ap[(wm*64 + mi*16 + l15)*32 + q];
    #pragma unroll
    for (int slab=0; slab<3; slab++){
        bf16x8 b0 = *(const bf16x8*)&Bp[(slab*64 + wn*32 + l15)*32 + q];
        bf16x8 b1 = *(const bf16x8*)&Bp[(slab*64 + wn*32 + 16 + l15)*32 + q];
        f32x4 (&acc)[4][2] = (slab==0)?ar:((slab==1)?az:a3);
        #pragma unroll
        for (int mi=0;mi<4;mi++){
            acc[mi][0] = __builtin_amdgcn_mfma_f32_16x16x32_bf16(a[mi], b0, acc[mi][0],0,0,0);
            acc[mi][1] = __builtin_amdgcn_mfma_f32_16x16x32_bf16(a[mi], b1, acc[mi][1],0,0,0);
        }
    }
}

// fused GRU cell, 2-phase double-buffered gload_lds staging (T3 minimum recipe)
__global__ __launch_bounds__(256,2) void k_gru3(
    const unsigned short* __restrict__ xg, const unsigned short* __restrict__ hbin,
    float* __restrict__ h,
    const unsigned short* __restrict__ Wihr, const unsigned short* __restrict__ Whhr,
    const float* __restrict__ bih, const float* __restrict__ bhh,
    unsigned short* __restrict__ hbout)
{
    __shared__ __align__(16) unsigned short As[2][128*32];  // 2 x 8KB
    __shared__ __align__(16) unsigned short Bs[2][192*32];  // 2 x 12KB
    const int tid = threadIdx.x, wid = tid>>6, lane = tid&63;
    const int wm = wid>>1, wn = wid&1;
    const int r0 = blockIdx.x*128, j0 = blockIdx.y*64;
    const int l15 = lane&15, lhi = lane>>4;
    const int cl = lane>>2;
    const int swz = ((lane&3) ^ (cl&3))*16;
    const int q = (lhi ^ (l15&3))*8;

    f32x4 ar[4][2]={}, az[4][2]={}, ain[4][2]={}, ahn[4][2]={};

    auto stageA = [&](int ks, int bs){
        char* Ld = (char*)&As[bs][0] + wid*2048;
        const char* src; size_t stride;
        if (ks < 9){ src = (const char*)xg   + (size_t)r0*576 + (size_t)ks*64;     stride = 576; }
        else       { src = (const char*)hbin + (size_t)r0*512 + (size_t)(ks-9)*64; stride = 512; }
        #pragma unroll
        for (int i=0;i<2;i++){
            int row = wid*32 + i*16 + cl;
            gload16(src + (size_t)row*stride + swz, Ld + i*1024);
        }
    };
    auto stageB = [&](int ks, int bs){
        char* Ld = (char*)&Bs[bs][0] + wid*3072;
        const char* src; size_t stride; int kb;
        if (ks < 9){ src = (const char*)Wihr; stride = 576; kb = ks; }
        else       { src = (const char*)Whhr; stride = 512; kb = ks-9; }
        #pragma unroll
        for (int i=0;i<3;i++){
            int j = wid*3 + i;
            int wrow = (j>>2)*256 + j0 + (j&3)*16 + cl;
            gload16(src + (size_t)wrow*stride + (size_t)kb*64 + swz, Ld + i*1024);
        }
    };

    stageA(0,0); stageB(0,0);
    __syncthreads();
    for (int ks=0; ks<9; ks++){
        int cur = ks&1;
        { stageA(ks+1, cur^1); stageB(ks+1, cur^1); }
        gtile(&As[cur][0], &Bs[cur][0], wm, wn, l15, q, ar, az, ain);
        __syncthreads();
    }
    for (int ks=9; ks<17; ks++){
        int cur = ks&1;
        if (ks<16){ stageA(ks+1, cur^1); stageB(ks+1, cur^1); }
        gtile(&As[cur][0], &Bs[cur][0], wm, wn, l15, q, ar, az, ahn);
        __syncthreads();
    }
    // ---- fused gate epilogue ----
    #pragma unroll
    for (int ni=0; ni<2; ni++){
        int col = j0 + wn*32 + ni*16 + l15;
        float br = bih[col]       + bhh[col];
        float bz = bih[col+HID]   + bhh[col+HID];
        float bi = bih[col+2*HID];
        float bh = bhh[col+2*HID];
        #pragma unroll
        for (int mi=0; mi<4; mi++){
            #pragma unroll
            for (int v=0; v<4; v++){
                size_t row = r0 + wm*64 + mi*16 + lhi*4 + v;
                float r  = sigf(ar[mi][ni][v] + br);
                float z  = sigf(az[mi][ni][v] + bz);
                float nn = tanhf(ain[mi][ni][v] + bi + r*(ahn[mi][ni][v] + bh));
                float ho = h[row*HID + col];
                float hv = (1.f - z)*nn + z*ho;
                h[row*HID + col] = hv;
                hbout[row*HID + col] = f2b(hv);
            }
        }
    }
}

// x_new = h @ Wfc^T + bfc ; write to out[:,p,:,:] and xprev
__global__ void k_fc(const float* __restrict__ h, const float* __restrict__ Wfc,
                     const float* __restrict__ bfc, float* __restrict__ outp,
                     float* __restrict__ xprev, int p){
    int w = threadIdx.x >> 6;
    int lane = threadIdx.x & 63;
    int row = blockIdx.x*4 + w;
    if (row >= ROWS) return;
    const float4* hv = (const float4*)(h + (size_t)row*HID);
    const float4* wv = (const float4*)Wfc;
    float4 a = hv[lane], b = wv[lane];
    float acc = a.x*b.x + a.y*b.y + a.z*b.z + a.w*b.w;
    for (int off=32;off;off>>=1) acc += __shfl_down(acc, off);
    if (lane==0){
        float v = acc + bfc[0];
        int bb = row / NN, n = row - bb*NN;
        outp[(size_t)(bb*PRED_L + p)*NN + n] = v;
        xprev[row] = v;
    }
}

extern "C" void kernel_launch(void* const* d_in, const int* in_sizes, int n_in,
                              void* d_out, int out_size, void* d_ws, size_t ws_size,
                              hipStream_t stream){
    const float* x_hist = (const float*)d_in[0];
    const float* feats  = (const float*)d_in[1];
    const int*   ei     = (const int*)d_in[2];
    const float* Wc     = (const float*)d_in[3];
    const float* bc     = (const float*)d_in[4];
    const float* Wih    = (const float*)d_in[5];
    const float* bih    = (const float*)d_in[6];
    const float* Whh    = (const float*)d_in[7];
    const float* bhh    = (const float*)d_in[8];
    const float* Wfc    = (const float*)d_in[9];
    const float* bfc    = (const float*)d_in[10];
    float* out = (float*)d_out;

    char* wsp = (char*)d_ws;
    size_t off = 0;
    auto alloc = [&](size_t bytes)->char*{
        char* p = wsp + off; off = (off + bytes + 255) & ~(size_t)255; return p;
    };
    int*   deg  = (int*)  alloc(NN*4);
    int*   cnt  = (int*)  alloc(NN*4);
    int*   coff = (int*)  alloc((NN+1)*4);
    int*   csrc = (int*)  alloc(NE*4);
    float* cw   = (float*)alloc(NE*4);
    float* xt   = (float*)alloc((size_t)ROWS*INUM*4);
    float* T1   = (float*)alloc((size_t)ROWS*INUM*4);
    unsigned short* ctx = (unsigned short*)alloc((size_t)ROWS*CTXW*2);
    unsigned short* xgb = (unsigned short*)alloc((size_t)ROWS*XGW*2);
    float* h    = (float*)alloc((size_t)ROWS*HID*4);
    unsigned short* hbA = (unsigned short*)alloc((size_t)ROWS*HID*2);
    unsigned short* hbB = (unsigned short*)alloc((size_t)ROWS*HID*2);
    float* xprev= (float*)alloc((size_t)ROWS*4);
    unsigned short* Wihr = (unsigned short*)alloc((size_t)768*XGW*2);
    unsigned short* Whhr = (unsigned short*)alloc((size_t)768*HID*2);
    unsigned short* Wctr = (unsigned short*)alloc((size_t)256*CTXW*2);

    hipMemsetAsync(deg, 0, NN*4, stream);
    hipMemsetAsync(cnt, 0, NN*4, stream);
    hipMemsetAsync(h,   0, (size_t)ROWS*HID*4, stream);
    hipMemsetAsync(hbA, 0, (size_t)ROWS*HID*2, stream);

    k_count<<<(NE+255)/256,256,0,stream>>>(ei, deg, cnt);
    k_prefix<<<1,64,0,stream>>>(cnt, coff);
    k_fill<<<(NN+255)/256,256,0,stream>>>(ei, deg, coff, csrc, cw);

    { int n = 768*XGW; k_f2b<<<(n+255)/256,256,0,stream>>>(Wih, Wihr, n); }
    { int n = 768*HID; k_f2b<<<(n+255)/256,256,0,stream>>>(Whh, Whhr, n); }
    { int n = 256*CTXW; k_wctr<<<(n+255)/256,256,0,stream>>>(Wc, Wctr); }

    unsigned short* hbin = hbA; unsigned short* hbout = hbB;
    dim3 gemmGrid(ROWS/128, HID/64);
    const int NT  = (ROWS*INUM+255)/256;
    const int NT8 = (ROWS*8+255)/256;

    auto step = [&](const float* ch0, int bstride, int choff, int tf){
        k_build_xt<<<NT,256,0,stream>>>(ch0, bstride, choff, feats, tf, xt, ctx, xgb);
        k_lx4<<<NT8,256,0,stream>>>(xt, coff, csrc, cw, nullptr, 1.f, T1, ctx + 32);
        k_lx4<<<NT8,256,0,stream>>>(T1, coff, csrc, cw, xt, 2.f, nullptr, ctx + 64);
        k_cheb2<<<gemmGrid,256,0,stream>>>(ctx, Wctr, bc, xgb);
        k_gru3<<<gemmGrid,256,0,stream>>>(xgb, hbin, h, Wihr, Whhr, bih, bhh, hbout);
        unsigned short* t = hbin; hbin = hbout; hbout = t;
    };

    for (int t=0;t<HIST_L-1;t++)
        step(x_hist, HIST_L*NN, t*NN, t+1);
    for (int p=0;p<PRED_L;p++){
        if (p==0) step(x_hist, HIST_L*NN, (HIST_L-1)*NN, HIST_L+p);
        else      step(xprev, NN, 0, HIST_L+p);
        k_fc<<<(ROWS+3)/4,256,0,stream>>>(h, Wfc, bfc, out, xprev, p);
    }
}